// Round 14
// baseline (192.668 us; speedup 1.0000x reference)
//
#include <hip/hip_runtime.h>
#include <hip/hip_bf16.h>

#define N_INS 16384
#define N_ATT 8192
#define KDIM  64

typedef __attribute__((ext_vector_type(8))) short bf16x8;
typedef __attribute__((ext_vector_type(4))) float f32x4;

// ws layout (bytes):
// 0:       bf16 Ucb[8192*64] (1 MiB, fragment-order tiles)  [K1 writes all]
// 1048576: float cpr[64][64]                                 [K1 writes all]
// 1064960: float cpc[32][64]                                 [K1 writes all]
// 1073152: float Aseg[4][4096]  (4 replicas, 64 KB; K1 zeroes, K2 atomics)
// 1138688: float Bseg[4][4096]  (4 replicas, 64 KB; K1 zeroes, K2 atomics)
// 1204224: double Gacc[96]   ([0,64)=G, [64,80)=Uu, [80,96)=Vv; K1 zeroes)
// 1204992: unsigned tickets[272] (shard s at [s*16], global at [256]; K1 zeroes)
#define OFF_UCB    0
#define OFF_CPR    1048576
#define OFF_CPC    1064960
#define OFF_ASEG   1073152
#define OFF_BSEG   1138688
#define OFF_GACC   1204224
#define OFF_TK     1204992

// R22: the 92us wall was the SEG phase, not heavy (proof: baseline->R21 heavy
// restructure changed k_main by 0.0us; R19's 8x seg rows tripled it). Old seg
// was thread-per-row argmax (64-line gathers) + a second full read + u-dot's
// third strided read. New: ONE coalesced pass, row-per-wave: load row (256B),
// wave-argmax (shfl+ballot first-max), LDS-atomic segsum, fused u-dot
// (shfl-sum, u*log2u). NBLK_U eliminated. k_prep convert inverted to
// coalesced-load/scatter-store. Heavy keeps R20 direct+dbuf.
#define NBLK_SEG   96             // K2 [0,96): fused argmax+segsum+u-dot (256 rows each)
#define NBLK_HEAVY 2048           // K2 [96, 2144)
#define NBLK_K2    (NBLK_SEG + NBLK_HEAVY)   // 2144 = 16 * 134

__device__ __forceinline__ unsigned short f2bf(float x) {
    unsigned u = __float_as_uint(x);
    u = (u + 0x7FFFu + ((u >> 16) & 1u)) >> 16;   // RNE
    return (unsigned short)u;
}

__device__ __forceinline__ float wave_red(float v) {
#pragma unroll
    for (int o = 32; o > 0; o >>= 1) v += __shfl_down(v, o, 64);
    return v;
}

// ---- K1: convert + colsums + zero ----
// blocks [0,128):   convert Uc->bf16 fragment tiles (coalesced LOADS, scattered
//                   16B stores — stores are fire-and-forget, gathers stall)
// blocks [128,192): Ur colsums (256 rows)  -> cpr[b]
// blocks [192,224): Uc colsums (256 rows)  -> cpc[b]
// block  224:       zero Aseg/Bseg (4 replicas each) /Gacc/tickets
__global__ __launch_bounds__(256)
void k_prep(const float* __restrict__ Ur, const float* __restrict__ Uc,
            float* __restrict__ cpr, float* __restrict__ cpc,
            unsigned short* __restrict__ Ucb,
            float* __restrict__ Aseg, float* __restrict__ Bseg,
            double* __restrict__ Gacc, unsigned* __restrict__ tickets) {
    __shared__ float cs2[256];
    int blk = blockIdx.x, tid = threadIdx.x;
    if (blk < 128) {
        // thread c handles source row r = c>>3, quad q = c&7 (32 B contiguous);
        // wave covers 2 KB contiguous. Dest chunk o: q<4 -> q*16+m ; else
        // 64+(q-4)*16+m with m=r&15, tile t=r>>4 (inverse of reader's map).
        int gid = blk * 256 + tid;
        for (int c = gid; c < N_ATT * 8; c += 32768) {
            int r = c >> 3, q = c & 7;
            const float* src = Uc + (size_t)r * 64 + q * 8;
            float4 x0 = ((const float4*)src)[0], x1 = ((const float4*)src)[1];
            uint4 v;
            v.x = (unsigned)f2bf(x0.x) | ((unsigned)f2bf(x0.y) << 16);
            v.y = (unsigned)f2bf(x0.z) | ((unsigned)f2bf(x0.w) << 16);
            v.z = (unsigned)f2bf(x1.x) | ((unsigned)f2bf(x1.y) << 16);
            v.w = (unsigned)f2bf(x1.z) | ((unsigned)f2bf(x1.w) << 16);
            int t = r >> 4, m = r & 15;
            int o = (q < 4) ? (q * 16 + m) : (64 + (q - 4) * 16 + m);
            *(uint4*)((unsigned char*)Ucb + ((size_t)t * 128 + o) * 16) = v;
        }
        return;
    }
    if (blk == 224) {
        float4 z4 = {0.f, 0.f, 0.f, 0.f};
        // 4 replicas x 4096 f32 = 4096 float4 each for A and B
        for (int i = tid; i < 4096; i += 256) ((float4*)Aseg)[i] = z4;
        for (int i = tid; i < 4096; i += 256) ((float4*)Bseg)[i] = z4;
        if (tid < 96) Gacc[tid] = 0.0;
        if (tid < 64) { tickets[tid] = 0u; tickets[64 + tid] = 0u;
                        tickets[128 + tid] = 0u; tickets[192 + tid] = 0u; }
        if (tid < 16) tickets[256 + tid] = 0u;
        return;
    }
    bool isUr = blk < 192;
    int b = isUr ? (blk - 128) : (blk - 192);
    const float* base = (isUr ? Ur : Uc) + (size_t)b * 256 * KDIM;
    float* dst = (isUr ? cpr : cpc) + b * 64;
    int col = tid & 63, r0 = tid >> 6;
    float s = 0.f;
    for (int r = r0; r < 256; r += 4) s += base[r * KDIM + col];
    cs2[tid] = s;
    __syncthreads();
    if (tid < 64) dst[tid] = cs2[tid] + cs2[tid + 64] + cs2[tid + 128] + cs2[tid + 192];
}

// ---- K2: fused seg (96) + heavy (2048, reg-dbuf) + final ----
__global__ __launch_bounds__(256)
void k_main(const float* __restrict__ Ur, const float* __restrict__ Uc,
            const unsigned char* __restrict__ Ucb,
            const float* __restrict__ cpr, const float* __restrict__ cpc,
            float* __restrict__ Aseg, float* __restrict__ Bseg,
            double* __restrict__ Gacc, unsigned* __restrict__ tickets,
            float* __restrict__ out) {
    // smem roles: seg: Part f32[4096] @0 (16K) + wvs f32[64] @16384
    //             finale: Prx @0, Pry @256, sc @512, red @1024..3072
    //             heavy: gshW @0 (16B)
    __shared__ __align__(16) unsigned char smem[16640];
    __shared__ int flagS;
    int tid = threadIdx.x, blk = blockIdx.x;
    int wvi = tid >> 6, lane = tid & 63;

    if (blk < NBLK_SEG) {
        // ---------- fused argmax + segsum + u-dot, one coalesced pass ----------
        float* Part = (float*)smem;                  // 4096 f32
        float* wvs  = (float*)(smem + 16384);        // 64 f32
        bool isUr = blk < 64;
        int b = isUr ? blk : (blk - 64);
        const float* M = isUr ? Ur : Uc;
        // 4-way replica sharding of the global fold target (contention /4)
        float* Seg = (isUr ? Aseg : Bseg) + ((b & 3) << 12);
        int base_row = b * 256;
        if (tid < 64) {
            const float* cpw = isUr ? cpc : cpr;     // colsums of OTHER matrix
            int nbw = isUr ? 32 : 64;
            float s = 0.f;
            for (int p = 0; p < nbw; ++p) s += cpw[p * 64 + tid];
            wvs[tid] = s;
        }
        for (int i = tid; i < 4096; i += 256) Part[i] = 0.f;
        __syncthreads();
        float wv = wvs[lane];
        float ulog = 0.f;
        const float* Mb = M + (size_t)(base_row + wvi * 64) * 64 + lane;
#pragma unroll 4
        for (int r = 0; r < 64; ++r) {
            float v = Mb[(size_t)r * 64];            // coalesced 256B row load
            // wave argmax, first-index tie-break (== jnp.argmax)
            float mx = v;
#pragma unroll
            for (int o = 32; o > 0; o >>= 1) mx = fmaxf(mx, __shfl_xor(mx, o, 64));
            unsigned long long msk = __ballot(v == mx);
            int idx = __ffsll((unsigned long long)msk) - 1;
            // fused u-dot: u = row . colsum(other)
            float pd = v * wv;
#pragma unroll
            for (int o = 32; o > 0; o >>= 1) pd += __shfl_xor(pd, o, 64);
            if (lane == 0) ulog += pd * __log2f(pd);
            atomicAdd(&Part[idx * 64 + lane], v);    // fire-and-forget ds_add
        }
        if (lane == 0)
            atomicAdd(&Gacc[(isUr ? 64 : 80) + (b & 15)], (double)ulog);
        __syncthreads();
        for (int i = tid; i < 4096; i += 256)        // coalesced global fold
            atomicAdd(&Seg[i], Part[i]);
    } else {
        // ---------- heavy: G += d*log2(d), MFMA, B direct from cache with
        // explicit register double-buffer (R20). No LDS/barriers in loop. ----------
        float* gshW = (float*)smem;
        int hb = blk - NBLK_SEG;
        int quad = lane >> 4, m = lane & 15;
        int rb = hb & 127, cc = hb >> 7;
        int row0 = rb * 128 + wvi * 32;
        bf16x8 a[2][2];
#pragma unroll
        for (int t = 0; t < 2; ++t) {
            int ridx = row0 + t * 16 + m;
            const float* rp = Ur + (size_t)ridx * 64 + quad * 8;
#pragma unroll
            for (int h = 0; h < 2; ++h) {
                const float* rph = rp + h * 32;
                float4 x0 = *(const float4*)rph;
                float4 x1 = *(const float4*)(rph + 4);
                bf16x8 f;
                f[0] = (short)f2bf(x0.x); f[1] = (short)f2bf(x0.y);
                f[2] = (short)f2bf(x0.z); f[3] = (short)f2bf(x0.w);
                f[4] = (short)f2bf(x1.x); f[5] = (short)f2bf(x1.y);
                f[6] = (short)f2bf(x1.z); f[7] = (short)f2bf(x1.w);
                a[t][h] = f;
            }
        }
        const unsigned char* gB = Ucb + (size_t)(cc * 32) * 2048;
        int loff = lane * 16;
        float g0 = 0.f, g1 = 0.f, g2 = 0.f, g3 = 0.f;  // break serial fmac chain
        // prologue: prefetch chunk 0 (4 KB = 2 B-tiles)
        bf16x8 n00 = *(const bf16x8*)(gB + loff);
        bf16x8 n01 = *(const bf16x8*)(gB + 1024 + loff);
        bf16x8 n10 = *(const bf16x8*)(gB + 2048 + loff);
        bf16x8 n11 = *(const bf16x8*)(gB + 3072 + loff);
#pragma unroll 1
        for (int ch = 0; ch < 16; ++ch) {
            bf16x8 c00 = n00, c01 = n01, c10 = n10, c11 = n11;
            if (ch < 15) {                           // issue next-chunk loads NOW
                const unsigned char* nb = gB + (size_t)(ch + 1) * 4096;
                n00 = *(const bf16x8*)(nb + loff);
                n01 = *(const bf16x8*)(nb + 1024 + loff);
                n10 = *(const bf16x8*)(nb + 2048 + loff);
                n11 = *(const bf16x8*)(nb + 3072 + loff);
            }
            f32x4 acc00 = {0.f,0.f,0.f,0.f}, acc01 = {0.f,0.f,0.f,0.f};
            f32x4 acc10 = {0.f,0.f,0.f,0.f}, acc11 = {0.f,0.f,0.f,0.f};
            acc00 = __builtin_amdgcn_mfma_f32_16x16x32_bf16(a[0][0], c00, acc00, 0, 0, 0);
            acc00 = __builtin_amdgcn_mfma_f32_16x16x32_bf16(a[0][1], c01, acc00, 0, 0, 0);
            acc10 = __builtin_amdgcn_mfma_f32_16x16x32_bf16(a[1][0], c00, acc10, 0, 0, 0);
            acc10 = __builtin_amdgcn_mfma_f32_16x16x32_bf16(a[1][1], c01, acc10, 0, 0, 0);
            acc01 = __builtin_amdgcn_mfma_f32_16x16x32_bf16(a[0][0], c10, acc01, 0, 0, 0);
            acc01 = __builtin_amdgcn_mfma_f32_16x16x32_bf16(a[0][1], c11, acc01, 0, 0, 0);
            acc11 = __builtin_amdgcn_mfma_f32_16x16x32_bf16(a[1][0], c10, acc11, 0, 0, 0);
            acc11 = __builtin_amdgcn_mfma_f32_16x16x32_bf16(a[1][1], c11, acc11, 0, 0, 0);
            // tile-sum permutation-invariant -> C/D layout irrelevant;
            // +eps*S dropped (~2e-6 vs d~16): mi_org shift ~2e-7 << thresh
#pragma unroll
            for (int e = 0; e < 4; ++e) {
                float d0 = acc00[e]; g0 += d0 * __log2f(d0);
                float d1 = acc01[e]; g1 += d1 * __log2f(d1);
                float d2 = acc10[e]; g2 += d2 * __log2f(d2);
                float d3 = acc11[e]; g3 += d3 * __log2f(d3);
            }
        }
        float gw = wave_red((g0 + g1) + (g2 + g3));
        if (lane == 0) gshW[wvi] = gw;
        __syncthreads();
        if (tid == 0) {
            float gs = gshW[0] + gshW[1] + gshW[2] + gshW[3];
            atomicAdd(&Gacc[hb & 63], (double)gs);
        }
    }

    // ---------- common tail: drain own atomics, line-padded sharded ticket ----------
    __builtin_amdgcn_s_waitcnt(0);                   // all this block's atomics acked
    __syncthreads();
    if (tid == 0) {
        flagS = 0;
        unsigned old = atomicAdd(&tickets[(blk & 15) << 4], 1u);  // own 64B line
        if (old == (NBLK_K2 / 16) - 1) {
            unsigned old2 = atomicAdd(&tickets[256], 1u);
            flagS = (old2 == 15u);
        }
    }
    __syncthreads();
    if (!flagS) return;

    // final: Aseg/Bseg/Gacc atomic-written (coherent); cpr/cpc boundary-coherent.
    // Pre-reduce the 4 fold replicas into replica 0 (coalesced, ~32K loads).
    for (int i = tid; i < 4096; i += 256) {
        Aseg[i] += Aseg[i + 4096] + Aseg[i + 8192] + Aseg[i + 12288];
        Bseg[i] += Bseg[i + 4096] + Bseg[i + 8192] + Bseg[i + 12288];
    }
    __syncthreads();
    float*  Prx = (float*)smem;
    float*  Pry = (float*)(smem + 256);
    double* sc  = (double*)(smem + 512);             // S,G,Uu,Vv
    double* red = (double*)(smem + 1024);            // 256 f64
    if (tid < 64) {
        double sa = 0.0, sb = 0.0;
        for (int p = 0; p < 64; ++p) sa += (double)cpr[p * 64 + tid];
        for (int p = 0; p < 32; ++p) sb += (double)cpc[p * 64 + tid];
        red[tid] = sa * sb;
        Prx[tid] = 0.f; Pry[tid] = 0.f;
    }
    __syncthreads();
    if (tid == 0) {
        double s = 0.0;
        for (int k = 0; k < 64; ++k) s += red[k];
        sc[0] = s;
        double gg = 0.0;
        for (int k = 0; k < 64; ++k) gg += Gacc[k];
        sc[1] = gg;
    } else if (tid == 1) {
        double s = 0.0;
        for (int k = 64; k < 80; ++k) s += Gacc[k];
        sc[2] = s;
    } else if (tid == 2) {
        double s = 0.0;
        for (int k = 80; k < 96; ++k) s += Gacc[k];
        sc[3] = s;
    }
    __syncthreads();
    double S = sc[0];
    int p = tid >> 2, q0 = (tid & 3) * 16;
    float tloc[16];
    {
        float prow_sum = 0.f;
        for (int qi = 0; qi < 16; ++qi) {
            int q = q0 + qi;
            double s = 0.0;
            for (int k = 0; k < 64; ++k)
                s += (double)Aseg[p * 64 + k] * (double)Bseg[q * 64 + k];
            float t = (float)(s / S);
            tloc[qi] = t;
            prow_sum += t;
            atomicAdd(&Pry[q], t);
        }
        atomicAdd(&Prx[p], prow_sum);
    }
    __syncthreads();
    {
        const double EPSd = 1e-15;
        double part = 0.0;
        for (int qi = 0; qi < 16; ++qi) {
            double t = (double)tloc[qi];
            double txy = (double)Prx[p] * (double)Pry[q0 + qi];
            part += t * log((t + EPSd) / (txy + EPSd));
        }
        red[tid] = part;
    }
    __syncthreads();
    for (int s2 = 128; s2 > 0; s2 >>= 1) {
        if (tid < s2) red[tid] += red[tid + s2];
        __syncthreads();
    }
    if (tid == 0) {
        const double inv_ln2 = 1.4426950408889634;
        double mi_red = red[0] * inv_ln2;
        double G = sc[1], Uu = sc[2], Vv = sc[3];
        double log2S = log(S) * inv_ln2;
        double mi_org = G / S + log2S - (Uu + Vv) / S;
        double loss = log(1.0 + fabs(1.0 - mi_red / mi_org));
        out[0] = (float)loss;
    }
}

extern "C" void kernel_launch(void* const* d_in, const int* in_sizes, int n_in,
                              void* d_out, int out_size, void* d_ws, size_t ws_size,
                              hipStream_t stream) {
    const float* Ur = (const float*)d_in[0];
    const float* Uc = (const float*)d_in[1];
    float* out = (float*)d_out;
    char* ws = (char*)d_ws;
    unsigned short* Ucb = (unsigned short*)(ws + OFF_UCB);
    float* cpr   = (float*)(ws + OFF_CPR);
    float* cpc   = (float*)(ws + OFF_CPC);
    float* Aseg  = (float*)(ws + OFF_ASEG);
    float* Bseg  = (float*)(ws + OFF_BSEG);
    double* Gacc = (double*)(ws + OFF_GACC);
    unsigned* tickets = (unsigned*)(ws + OFF_TK);

    k_prep<<<225, 256, 0, stream>>>(Ur, Uc, cpr, cpc, Ucb, Aseg, Bseg, Gacc, tickets);
    k_main<<<NBLK_K2, 256, 0, stream>>>(Ur, Uc, (const unsigned char*)Ucb,
                                        cpr, cpc, Aseg, Bseg, Gacc, tickets, out);
}

// Round 17
// 149.801 us; speedup vs baseline: 1.2862x; 1.2862x over previous
//
#include <hip/hip_runtime.h>
#include <hip/hip_bf16.h>

#define N_INS 16384
#define N_ATT 8192
#define KDIM  64

typedef __attribute__((ext_vector_type(8))) short bf16x8;
typedef __attribute__((ext_vector_type(4))) float f32x4;

// ws layout (bytes):
// 0:       bf16 Ucb[8192*64] (1 MiB, fragment-order tiles)  [K1 writes all]
// 1048576: float cpr[128][64] (32 KB, 128-row partial colsums of Ur)
// 1081344: float cpc[64][64]  (16 KB, 128-row partial colsums of Uc)
// 1097728: float Aseg[4][4096]  (4 replicas, 64 KB; K1 zeroes, K2 atomics)
// 1163264: float Bseg[4][4096]  (4 replicas, 64 KB; K1 zeroes, K2 atomics)
// 1228800: double Gacc[96]   ([0,64)=G, [64,80)=Uu, [80,96)=Vv; K1 zeroes)
// 1229568: unsigned tickets[272] (shard s at [s*16], global at [256]; K1 zeroes)
#define OFF_UCB    0
#define OFF_CPR    1048576
#define OFF_CPC    1081344
#define OFF_ASEG   1097728
#define OFF_BSEG   1163264
#define OFF_GACC   1228800
#define OFF_TK     1229568

// R23: R22's shuffle-seg regressed (92->124us: 12 dependent DS-shuffles/row
// killed MLP; old gather-argmax had 4096 loads in flight). k_main REVERTED to
// R21 (measured 92.0us). New target: k_prep was ~65us (end2end minus k_main)
// for 8MB of work -> scalar 4B colsum loads + 225 blocks (1 wave/SIMD). Fix:
// float4 colsum loads (1KB/wave-inst), 128-row blocks (192 colsum blocks),
// grid 321. cpr[128][64], cpc[64][64].
#define NBLK_SEG   96             // K2 [0,96): argmax+segsum (256 rows each)
#define NBLK_U     96             // K2 [96,192): u-dot
#define NBLK_HEAVY 2048           // K2 [192, 2240)
#define NBLK_K2    (NBLK_SEG + NBLK_U + NBLK_HEAVY)   // 2240 = 16 * 140

__device__ __forceinline__ unsigned short f2bf(float x) {
    unsigned u = __float_as_uint(x);
    u = (u + 0x7FFFu + ((u >> 16) & 1u)) >> 16;   // RNE
    return (unsigned short)u;
}

__device__ __forceinline__ float wave_red(float v) {
#pragma unroll
    for (int o = 32; o > 0; o >>= 1) v += __shfl_down(v, o, 64);
    return v;
}

// ---- K1: convert + colsums + zero ----
// blocks [0,128):   convert Uc->bf16 fragment tiles (coalesced loads, scattered
//                   16B stores — stores are fire-and-forget, gathers stall)
// blocks [128,256): Ur colsums (128 rows, float4 loads) -> cpr[b]
// blocks [256,320): Uc colsums (128 rows, float4 loads) -> cpc[b]
// block  320:       zero Aseg/Bseg (4 replicas each) /Gacc/tickets
__global__ __launch_bounds__(256)
void k_prep(const float* __restrict__ Ur, const float* __restrict__ Uc,
            float* __restrict__ cpr, float* __restrict__ cpc,
            unsigned short* __restrict__ Ucb,
            float* __restrict__ Aseg, float* __restrict__ Bseg,
            double* __restrict__ Gacc, unsigned* __restrict__ tickets) {
    __shared__ float4 part[256];
    int blk = blockIdx.x, tid = threadIdx.x;
    if (blk < 128) {
        // thread c handles source row r = c>>3, quad q = c&7 (32 B contiguous);
        // wave covers 2 KB contiguous. Dest chunk o: q<4 -> q*16+m ; else
        // 64+(q-4)*16+m with m=r&15, tile t=r>>4 (inverse of reader's map).
        int gid = blk * 256 + tid;
        for (int c = gid; c < N_ATT * 8; c += 32768) {
            int r = c >> 3, q = c & 7;
            const float* src = Uc + (size_t)r * 64 + q * 8;
            float4 x0 = ((const float4*)src)[0], x1 = ((const float4*)src)[1];
            uint4 v;
            v.x = (unsigned)f2bf(x0.x) | ((unsigned)f2bf(x0.y) << 16);
            v.y = (unsigned)f2bf(x0.z) | ((unsigned)f2bf(x0.w) << 16);
            v.z = (unsigned)f2bf(x1.x) | ((unsigned)f2bf(x1.y) << 16);
            v.w = (unsigned)f2bf(x1.z) | ((unsigned)f2bf(x1.w) << 16);
            int t = r >> 4, m = r & 15;
            int o = (q < 4) ? (q * 16 + m) : (64 + (q - 4) * 16 + m);
            *(uint4*)((unsigned char*)Ucb + ((size_t)t * 128 + o) * 16) = v;
        }
        return;
    }
    if (blk == 320) {
        float4 z4 = {0.f, 0.f, 0.f, 0.f};
        // 4 replicas x 4096 f32 = 4096 float4 each for A and B
        for (int i = tid; i < 4096; i += 256) ((float4*)Aseg)[i] = z4;
        for (int i = tid; i < 4096; i += 256) ((float4*)Bseg)[i] = z4;
        if (tid < 96) Gacc[tid] = 0.0;
        if (tid < 64) { tickets[tid] = 0u; tickets[64 + tid] = 0u;
                        tickets[128 + tid] = 0u; tickets[192 + tid] = 0u; }
        if (tid < 16) tickets[256 + tid] = 0u;
        return;
    }
    // ---- colsums: 128 rows per block, float4 loads (1 KB per wave-inst) ----
    bool isUr = blk < 256;
    int b = isUr ? (blk - 128) : (blk - 256);
    const float* base = (isUr ? Ur : Uc) + (size_t)b * 128 * KDIM;
    float* dst = (isUr ? cpr : cpc) + b * 64;
    int cg = tid & 15, g = tid >> 4;                 // col-group [0,16), row-group [0,16)
    float4 s4 = {0.f, 0.f, 0.f, 0.f};
    const float* p0 = base + (size_t)g * 64 + cg * 4;
#pragma unroll
    for (int r = 0; r < 8; ++r) {                    // rows g, g+16, ..., g+112
        float4 v = *(const float4*)(p0 + (size_t)r * 16 * 64);
        s4.x += v.x; s4.y += v.y; s4.z += v.z; s4.w += v.w;
    }
    part[tid] = s4;
    __syncthreads();
    if (tid < 64) {
        int cg2 = tid >> 2, sub = tid & 3;
        float s = 0.f;
#pragma unroll
        for (int g2 = 0; g2 < 16; ++g2)
            s += ((const float*)&part[g2 * 16 + cg2])[sub];
        dst[tid] = s;
    }
}

// ---- K2: argmax/segsum (96) + u-dots (96) + heavy (2048, reg-dbuf) + final ----
// (R21 structure verbatim — measured 92.0us; only cpr/cpc partial counts changed)
__global__ __launch_bounds__(256)
void k_main(const float* __restrict__ Ur, const float* __restrict__ Uc,
            const unsigned char* __restrict__ Ucb,
            const float* __restrict__ cpr, const float* __restrict__ cpc,
            float* __restrict__ Aseg, float* __restrict__ Bseg,
            double* __restrict__ Gacc, unsigned* __restrict__ tickets,
            float* __restrict__ out) {
    // smem roles: seg: Part f32[4096] @0 (16K) + bins int[256] @16384 (1K)
    //             finale: Prx @0, Pry @256, sc @512, red @1024..3072
    //             heavy: gshW @0 (16B)
    __shared__ __align__(16) unsigned char smem[17408];
    __shared__ int flagS;
    int tid = threadIdx.x, blk = blockIdx.x;
    int wvi = tid >> 6, lane = tid & 63;

    if (blk < NBLK_SEG) {
        // ---------- argmax + segment-sum, 256 rows (R17 structure) ----------
        float* Part = (float*)smem;                  // 4096 f32
        int*   bins = (int*)(smem + 16384);          // 256 ints
        bool isUr = blk < 64;
        int b = isUr ? blk : (blk - 64);
        const float* M = isUr ? Ur : Uc;
        // 4-way replica sharding of the global fold target (contention /4)
        float* Seg = (isUr ? Aseg : Bseg) + ((b & 3) << 12);
        int base_row = b * 256;
        for (int i = tid; i < 4096; i += 256) Part[i] = 0.f;
        __syncthreads();
        {   // phase 1: row-per-thread argmax (first-max tie-break, as jnp.argmax)
            const float* rp = M + (size_t)(base_row + tid) * KDIM;
            float best = -1e30f; int bidx = 0;
#pragma unroll
            for (int k = 0; k < 64; k += 4) {
                float4 v = *(const float4*)(rp + k);
                if (v.x > best) { best = v.x; bidx = k; }
                if (v.y > best) { best = v.y; bidx = k + 1; }
                if (v.z > best) { best = v.z; bidx = k + 2; }
                if (v.w > best) { best = v.w; bidx = k + 3; }
            }
            bins[tid] = bidx;
        }
        __syncthreads();
        {   // phase 2: one fire-and-forget ds_add per row per wave
            int r0 = wvi * 64;
            const float* Mb = M + (size_t)(base_row + r0) * 64 + lane;
#pragma unroll 4
            for (int r = 0; r < 64; ++r) {
                int bb = bins[r0 + r];
                float val = Mb[(size_t)r * 64];
                atomicAdd(&Part[bb * 64 + lane], val);
            }
        }
        __syncthreads();
        for (int i = tid; i < 4096; i += 256)        // coalesced global fold
            atomicAdd(&Seg[i], Part[i]);
    } else if (blk < NBLK_SEG + NBLK_U) {
        // ---------- u-dot: u=row.colsum(other), Gacc += u*log2(u) ----------
        float* wv = (float*)smem;
        bool isUr = blk < (NBLK_SEG + 64);
        int b = isUr ? (blk - NBLK_SEG) : (blk - NBLK_SEG - 64);
        const float* M = isUr ? Ur : Uc;
        int base_row = b * 256;
        if (tid < 64) {
            const float* cpw = isUr ? cpc : cpr;     // colsums of OTHER matrix
            int nbw = isUr ? 64 : 128;               // cpc: 64 partials, cpr: 128
            float s = 0.f;
            for (int p = 0; p < nbw; ++p) s += cpw[p * 64 + tid];
            wv[tid] = s;
        }
        __syncthreads();
        const float* rp = M + (size_t)(base_row + tid) * KDIM;
        float u = 0.f;
#pragma unroll
        for (int k = 0; k < 64; k += 4) {
            float4 v = *(const float4*)(rp + k);
            u += v.x * wv[k] + v.y * wv[k + 1] + v.z * wv[k + 2] + v.w * wv[k + 3];
        }
        float pw = wave_red(u * __log2f(u));
        if (lane == 0)
            atomicAdd(&Gacc[(isUr ? 64 : 80) + (b & 15)], (double)pw);
    } else {
        // ---------- heavy: G += d*log2(d), MFMA, B direct from cache with
        // explicit register double-buffer (R20): prefetch chunk ch+1 into
        // n-regs while c-regs feed 8 MFMA + 16 log2-quads. No LDS/barriers. ----------
        float* gshW = (float*)smem;
        int hb = blk - NBLK_SEG - NBLK_U;
        int quad = lane >> 4, m = lane & 15;
        int rb = hb & 127, cc = hb >> 7;
        int row0 = rb * 128 + wvi * 32;
        bf16x8 a[2][2];
#pragma unroll
        for (int t = 0; t < 2; ++t) {
            int ridx = row0 + t * 16 + m;
            const float* rp = Ur + (size_t)ridx * 64 + quad * 8;
#pragma unroll
            for (int h = 0; h < 2; ++h) {
                const float* rph = rp + h * 32;
                float4 x0 = *(const float4*)rph;
                float4 x1 = *(const float4*)(rph + 4);
                bf16x8 f;
                f[0] = (short)f2bf(x0.x); f[1] = (short)f2bf(x0.y);
                f[2] = (short)f2bf(x0.z); f[3] = (short)f2bf(x0.w);
                f[4] = (short)f2bf(x1.x); f[5] = (short)f2bf(x1.y);
                f[6] = (short)f2bf(x1.z); f[7] = (short)f2bf(x1.w);
                a[t][h] = f;
            }
        }
        const unsigned char* gB = Ucb + (size_t)(cc * 32) * 2048;
        int loff = lane * 16;
        float g0 = 0.f, g1 = 0.f, g2 = 0.f, g3 = 0.f;  // break serial fmac chain
        // prologue: prefetch chunk 0 (4 KB = 2 B-tiles)
        bf16x8 n00 = *(const bf16x8*)(gB + loff);
        bf16x8 n01 = *(const bf16x8*)(gB + 1024 + loff);
        bf16x8 n10 = *(const bf16x8*)(gB + 2048 + loff);
        bf16x8 n11 = *(const bf16x8*)(gB + 3072 + loff);
#pragma unroll 1
        for (int ch = 0; ch < 16; ++ch) {
            bf16x8 c00 = n00, c01 = n01, c10 = n10, c11 = n11;
            if (ch < 15) {                           // issue next-chunk loads NOW
                const unsigned char* nb = gB + (size_t)(ch + 1) * 4096;
                n00 = *(const bf16x8*)(nb + loff);
                n01 = *(const bf16x8*)(nb + 1024 + loff);
                n10 = *(const bf16x8*)(nb + 2048 + loff);
                n11 = *(const bf16x8*)(nb + 3072 + loff);
            }
            f32x4 acc00 = {0.f,0.f,0.f,0.f}, acc01 = {0.f,0.f,0.f,0.f};
            f32x4 acc10 = {0.f,0.f,0.f,0.f}, acc11 = {0.f,0.f,0.f,0.f};
            acc00 = __builtin_amdgcn_mfma_f32_16x16x32_bf16(a[0][0], c00, acc00, 0, 0, 0);
            acc00 = __builtin_amdgcn_mfma_f32_16x16x32_bf16(a[0][1], c01, acc00, 0, 0, 0);
            acc10 = __builtin_amdgcn_mfma_f32_16x16x32_bf16(a[1][0], c00, acc10, 0, 0, 0);
            acc10 = __builtin_amdgcn_mfma_f32_16x16x32_bf16(a[1][1], c01, acc10, 0, 0, 0);
            acc01 = __builtin_amdgcn_mfma_f32_16x16x32_bf16(a[0][0], c10, acc01, 0, 0, 0);
            acc01 = __builtin_amdgcn_mfma_f32_16x16x32_bf16(a[0][1], c11, acc01, 0, 0, 0);
            acc11 = __builtin_amdgcn_mfma_f32_16x16x32_bf16(a[1][0], c10, acc11, 0, 0, 0);
            acc11 = __builtin_amdgcn_mfma_f32_16x16x32_bf16(a[1][1], c11, acc11, 0, 0, 0);
            // tile-sum permutation-invariant -> C/D layout irrelevant;
            // +eps*S dropped (~2e-6 vs d~16): mi_org shift ~2e-7 << thresh
#pragma unroll
            for (int e = 0; e < 4; ++e) {
                float d0 = acc00[e]; g0 += d0 * __log2f(d0);
                float d1 = acc01[e]; g1 += d1 * __log2f(d1);
                float d2 = acc10[e]; g2 += d2 * __log2f(d2);
                float d3 = acc11[e]; g3 += d3 * __log2f(d3);
            }
        }
        float gw = wave_red((g0 + g1) + (g2 + g3));
        if (lane == 0) gshW[wvi] = gw;
        __syncthreads();
        if (tid == 0) {
            float gs = gshW[0] + gshW[1] + gshW[2] + gshW[3];
            atomicAdd(&Gacc[hb & 63], (double)gs);
        }
    }

    // ---------- common tail: drain own atomics, line-padded sharded ticket ----------
    __builtin_amdgcn_s_waitcnt(0);                   // all this block's atomics acked
    __syncthreads();
    if (tid == 0) {
        flagS = 0;
        unsigned old = atomicAdd(&tickets[(blk & 15) << 4], 1u);  // own 64B line
        if (old == (NBLK_K2 / 16) - 1) {
            unsigned old2 = atomicAdd(&tickets[256], 1u);
            flagS = (old2 == 15u);
        }
    }
    __syncthreads();
    if (!flagS) return;

    // final: Aseg/Bseg/Gacc atomic-written (coherent); cpr/cpc boundary-coherent.
    // Pre-reduce the 4 fold replicas into replica 0 (coalesced, ~32K loads).
    for (int i = tid; i < 4096; i += 256) {
        Aseg[i] += Aseg[i + 4096] + Aseg[i + 8192] + Aseg[i + 12288];
        Bseg[i] += Bseg[i + 4096] + Bseg[i + 8192] + Bseg[i + 12288];
    }
    __syncthreads();
    float*  Prx = (float*)smem;
    float*  Pry = (float*)(smem + 256);
    double* sc  = (double*)(smem + 512);             // S,G,Uu,Vv
    double* red = (double*)(smem + 1024);            // 256 f64
    if (tid < 64) {
        double sa = 0.0, sb = 0.0;
        for (int p = 0; p < 128; ++p) sa += (double)cpr[p * 64 + tid];
        for (int p = 0; p < 64; ++p)  sb += (double)cpc[p * 64 + tid];
        red[tid] = sa * sb;
        Prx[tid] = 0.f; Pry[tid] = 0.f;
    }
    __syncthreads();
    if (tid == 0) {
        double s = 0.0;
        for (int k = 0; k < 64; ++k) s += red[k];
        sc[0] = s;
        double gg = 0.0;
        for (int k = 0; k < 64; ++k) gg += Gacc[k];
        sc[1] = gg;
    } else if (tid == 1) {
        double s = 0.0;
        for (int k = 64; k < 80; ++k) s += Gacc[k];
        sc[2] = s;
    } else if (tid == 2) {
        double s = 0.0;
        for (int k = 80; k < 96; ++k) s += Gacc[k];
        sc[3] = s;
    }
    __syncthreads();
    double S = sc[0];
    int p = tid >> 2, q0 = (tid & 3) * 16;
    float tloc[16];
    {
        float prow_sum = 0.f;
        for (int qi = 0; qi < 16; ++qi) {
            int q = q0 + qi;
            double s = 0.0;
            for (int k = 0; k < 64; ++k)
                s += (double)Aseg[p * 64 + k] * (double)Bseg[q * 64 + k];
            float t = (float)(s / S);
            tloc[qi] = t;
            prow_sum += t;
            atomicAdd(&Pry[q], t);
        }
        atomicAdd(&Prx[p], prow_sum);
    }
    __syncthreads();
    {
        const double EPSd = 1e-15;
        double part = 0.0;
        for (int qi = 0; qi < 16; ++qi) {
            double t = (double)tloc[qi];
            double txy = (double)Prx[p] * (double)Pry[q0 + qi];
            part += t * log((t + EPSd) / (txy + EPSd));
        }
        red[tid] = part;
    }
    __syncthreads();
    for (int s2 = 128; s2 > 0; s2 >>= 1) {
        if (tid < s2) red[tid] += red[tid + s2];
        __syncthreads();
    }
    if (tid == 0) {
        const double inv_ln2 = 1.4426950408889634;
        double mi_red = red[0] * inv_ln2;
        double G = sc[1], Uu = sc[2], Vv = sc[3];
        double log2S = log(S) * inv_ln2;
        double mi_org = G / S + log2S - (Uu + Vv) / S;
        double loss = log(1.0 + fabs(1.0 - mi_red / mi_org));
        out[0] = (float)loss;
    }
}

extern "C" void kernel_launch(void* const* d_in, const int* in_sizes, int n_in,
                              void* d_out, int out_size, void* d_ws, size_t ws_size,
                              hipStream_t stream) {
    const float* Ur = (const float*)d_in[0];
    const float* Uc = (const float*)d_in[1];
    float* out = (float*)d_out;
    char* ws = (char*)d_ws;
    unsigned short* Ucb = (unsigned short*)(ws + OFF_UCB);
    float* cpr   = (float*)(ws + OFF_CPR);
    float* cpc   = (float*)(ws + OFF_CPC);
    float* Aseg  = (float*)(ws + OFF_ASEG);
    float* Bseg  = (float*)(ws + OFF_BSEG);
    double* Gacc = (double*)(ws + OFF_GACC);
    unsigned* tickets = (unsigned*)(ws + OFF_TK);

    k_prep<<<321, 256, 0, stream>>>(Ur, Uc, cpr, cpc, Ucb, Aseg, Bseg, Gacc, tickets);
    k_main<<<NBLK_K2, 256, 0, stream>>>(Ur, Uc, (const unsigned char*)Ucb,
                                        cpr, cpc, Aseg, Bseg, Gacc, tickets, out);
}